// Round 8
// baseline (232.134 us; speedup 1.0000x reference)
//
#include <hip/hip_runtime.h>
#include <hip/hip_fp16.h>

#define NPOS 26688

struct PairInfo {
  int iq, v, Hs, gH, gW, base, per;
  unsigned magicPer, magicW;
  int tOfs, tN, tCb;     // teacher compact: texel offset, #cols, col base
  int sN, sCb;           // student compact: #cols, col base (locals: 12,0)
  float tx1, tx2, ty1, ty2;
  float sx1, sx2, sy1, sy2;
};

// magic = ceil(2^32/d); error-term checked for all used ranges
__constant__ PairInfo g_pairs[6] = {
  {0,1,32,25,24,    0,600, 7158279u,178956971u,    0,2, 7, 22,5, -0.80f,0.70f,-0.500f,-0.475f,  -0.90f,0.60f,-0.60f,0.60f},
  {0,2,12,25,24, 4800,600, 7158279u,178956971u,  512,2,17, 12,0, -0.75f,0.75f, 0.100f, 0.125f,  -0.80f,0.80f,-0.80f,0.80f},
  {0,3,12,22,24, 9600,528, 8134408u,178956971u, 1024,2,12, 12,0, -0.60f,0.90f,-0.200f,-0.178f,  -0.70f,0.90f,-0.90f,0.70f},
  {1,0,32,22,24,13824,528, 8134408u,178956971u, 1536,2,20, 24,7, -0.70f,0.80f, 0.300f, 0.322f,  -0.85f,0.65f,-0.50f,0.90f},
  {1,2,12,24,22,18048,528, 8134408u,195225787u, 2048,3,13, 12,0, -0.90f,0.50f,-0.100f,-0.076f,  -0.60f,0.95f,-0.95f,0.60f},
  {1,3,12,24,23,22272,552, 7780739u,186737709u, 2816,3,18, 12,0, -0.50f,0.95f, 0.200f, 0.224f,  -0.90f,0.90f,-0.40f,0.95f},
};

// compact-teacher write entries (x=-100 pads never match)
__constant__ int g_tentX[2][8] = {
  { 7, 8,12,13,17,18,-100,-100},
  {13,14,15,18,19,20,  20,  21},
};
__constant__ int g_tentO[2][8] = {
  {   0,   0,1024,1024, 512, 512,   0,   0},
  {2048,2048,2048,2816,2816,2816,1536,1536},
};
__constant__ int g_tentN[2][8] = {
  {2,2,2,2,2,2,2,2},
  {3,3,3,3,3,3,2,2},
};
__constant__ int g_tentC[2][8] = {
  {0,1,0,1,0,1,0,0},
  {0,1,2,0,1,2,0,1},
};
// probs-kernel texel decode tables
__constant__ int g_cumTex[6] = {0, 512, 1024, 1536, 2048, 2816};
__constant__ int g_tN[6]    = {2, 2, 2, 2, 3, 3};
__constant__ int g_tCb[6]   = {7, 17, 12, 20, 13, 18};

__device__ inline float get_invtemp(const int* __restrict__ ep) {
  int e = ep[0];
  e = e < 0 ? 0 : (e > 99 ? 99 : e);
  float temp = (e < 30) ? (0.04f + (float)e * (0.03f / 29.0f)) : 0.07f;
  return 1.0f / temp;
}

__device__ inline float sel4(const float4& v, int q) {
  return q == 0 ? v.x : q == 1 ? v.y : q == 2 ? v.z : v.w;
}

typedef _Float16 hv2 __attribute__((ext_vector_type(2)));
__device__ inline float fdot2f(__half2 a, __half2 b, float c) {
#if defined(__has_builtin)
#if __has_builtin(__builtin_amdgcn_fdot2)
  return __builtin_amdgcn_fdot2(*reinterpret_cast<hv2*>(&a),
                                *reinterpret_cast<hv2*>(&b), c, false);
#else
  float2 af = __half22float2(a), bf = __half22float2(b);
  return fmaf(af.x, bf.x, fmaf(af.y, bf.y, c));
#endif
#else
  float2 af = __half22float2(a), bf = __half22float2(b);
  return fmaf(af.x, bf.x, fmaf(af.y, bf.y, c));
#endif
}

// ============ phase1: stats[0,1024) | t12[1024,3072) | t32[3072,16384) ============
__global__ __launch_bounds__(256) void dino_phase1(
    const float* __restrict__ tg0, const float* __restrict__ tg1,
    const float* __restrict__ cen, const int* __restrict__ ep,
    float* __restrict__ part_m, float* __restrict__ part_s,
    __half* __restrict__ Tc,
    const float* __restrict__ sl0, const float* __restrict__ sl1,
    __half* __restrict__ Sl0, __half* __restrict__ Sl1,
    const float* __restrict__ sg0, const float* __restrict__ sg1,
    __half* __restrict__ Sg0, __half* __restrict__ Sg1) {
  __shared__ float smem[2320];          // 9280 B: t12 tile is the max user
  int bid = blockIdx.x;
  int t = threadIdx.x;

  if (bid < 1024) {
    // ---------- streaming stats: (view,b,cg32), contiguous 128KB read ----------
    int cg = bid & 63;
    int b = (bid >> 6) & 7;
    int view = bid >> 9;                // [0,2)
    const float* __restrict__ src = view ? tg1 : tg0;
    float invtemp = get_invtemp(ep);
    float* cenl = smem;                 // 32 floats
    if (t < 32) cenl[t] = cen[cg * 32 + t];
    __syncthreads();

    int y = t >> 3, x0 = (t & 7) * 4;   // thread owns texels y*32 + x0..x0+3
    const float* base = src + ((size_t)(b * 2048 + cg * 32)) * 1024 + t * 4;

    float4 m4 = make_float4(-1e30f, -1e30f, -1e30f, -1e30f);
    float4 s4 = make_float4(0.f, 0.f, 0.f, 0.f);
#pragma unroll
    for (int ch = 0; ch < 4; ++ch) {
      float4 lg[8];
#pragma unroll
      for (int k = 0; k < 8; ++k) {
        float4 v = *reinterpret_cast<const float4*>(base + (size_t)(ch * 8 + k) * 1024);
        float cv = cenl[ch * 8 + k];
        lg[k].x = (v.x - cv) * invtemp; lg[k].y = (v.y - cv) * invtemp;
        lg[k].z = (v.z - cv) * invtemp; lg[k].w = (v.w - cv) * invtemp;
      }
      float4 cm = lg[0];
#pragma unroll
      for (int k = 1; k < 8; ++k) {
        cm.x = fmaxf(cm.x, lg[k].x); cm.y = fmaxf(cm.y, lg[k].y);
        cm.z = fmaxf(cm.z, lg[k].z); cm.w = fmaxf(cm.w, lg[k].w);
      }
      float4 ns = make_float4(0.f, 0.f, 0.f, 0.f);
#pragma unroll
      for (int k = 0; k < 8; ++k) {
        ns.x += __expf(lg[k].x - cm.x); ns.y += __expf(lg[k].y - cm.y);
        ns.z += __expf(lg[k].z - cm.z); ns.w += __expf(lg[k].w - cm.w);
      }
      float mn;
      mn = fmaxf(m4.x, cm.x); s4.x = s4.x * __expf(m4.x - mn) + ns.x * __expf(cm.x - mn); m4.x = mn;
      mn = fmaxf(m4.y, cm.y); s4.y = s4.y * __expf(m4.y - mn) + ns.y * __expf(cm.y - mn); m4.y = mn;
      mn = fmaxf(m4.z, cm.z); s4.z = s4.z * __expf(m4.z - mn) + ns.z * __expf(cm.z - mn); m4.z = mn;
      mn = fmaxf(m4.w, cm.w); s4.w = s4.w * __expf(m4.w - mn) + ns.w * __expf(cm.w - mn); m4.w = mn;
    }
    size_t prow = ((size_t)((view * 8 + b) * 64 + cg)) * 1024 + t * 4;
    *reinterpret_cast<float4*>(part_m + prow) = m4;
    *reinterpret_cast<float4*>(part_s + prow) = s4;

    // pass 2: owner lanes re-read their sampled column from L2, write 64B dlogit
#pragma unroll
    for (int e = 0; e < 8; ++e) {
      int ex = g_tentX[view][e];
      int d = ex - x0;
      if (d >= 0 && d < 4) {
        float mm = sel4(m4, d);
        int tex = g_tentO[view][e] + (b * 32 + y) * g_tentN[view][e] + g_tentC[view][e];
        tex = min(max(tex, 0), 3583);
        const float* cp = src + ((size_t)(b * 2048 + cg * 32)) * 1024 + y * 32 + ex;
        __half hv[32];
#pragma unroll
        for (int c = 0; c < 32; ++c)
          hv[c] = __float2half((cp[(size_t)c * 1024] - cenl[c]) * invtemp - mm);
        uint4* dst = reinterpret_cast<uint4*>(Tc + (size_t)tex * 2048 + cg * 32);
        const uint4* sv = reinterpret_cast<const uint4*>(hv);
        dst[0] = sv[0]; dst[1] = sv[1]; dst[2] = sv[2]; dst[3] = sv[3];
      }
    }
    return;
  }

  if (bid < 3072) {
    // ---------- student 12x12 transpose, 16 ch/block: 2048 = v(2)*b(8)*ct(128) ----------
    float* tile = smem;                 // 16*145 = 2320
    int lb = bid - 1024;
    int ct = lb & 127;
    int g = lb >> 7;
    int b = g & 7;
    int vv = g >> 3;
    const float* __restrict__ src = vv ? sl1 : sl0;
    __half* __restrict__ dst = vv ? Sl1 : Sl0;
    const float* sp = src + ((size_t)(b * 2048 + ct * 16)) * 144;
#pragma unroll
    for (int k = 0; k < 9; ++k) {       // 2304 contiguous floats in
      int idx = t + 256 * k;
      int c = idx / 144;
      int yx = idx - c * 144;
      tile[c * 145 + yx] = sp[idx] * 10.f;
    }
    __syncthreads();
    __half* dp = dst + ((size_t)(b * 144)) * 2048 + ct * 16;
#pragma unroll
    for (int k = 0; k < 2; ++k) {       // 288 float4 chunks out
      int u = t + 256 * k;
      if (u < 288) {
        int yx = u >> 1, q8 = (u & 1) * 8;
        __half hv[8];
#pragma unroll
        for (int j = 0; j < 8; ++j) hv[j] = __float2half(tile[(q8 + j) * 145 + yx]);
        *reinterpret_cast<float4*>(dp + (size_t)yx * 2048 + q8) =
            *reinterpret_cast<float4*>(hv);
      }
    }
    return;
  }

  // ---------- student-global windowed transpose: 13312 = which(2)*b(8)*y(26)*ct(32) ----------
  float* tile = smem;                   // 64*33 = 2112
  int lb = bid - 3072;
  int ct = lb & 31;
  int t2 = lb >> 5;                     // [0,416)
  int yi = t2 % 26;
  int g = t2 / 26;                      // [0,16)
  int y = yi + 1;                       // rows 1..26 only (sampled window)
  int b = g & 7;
  int which = g >> 3;
  const float* __restrict__ src = which ? sg1 : sg0;
  __half* __restrict__ dst = which ? Sg1 : Sg0;
  int cb = which ? 5 : 7;
  int n = which ? 22 : 24;

  int xg = t & 7, ch = t >> 3;
  const float* sp = src + (((size_t)(b * 2048 + ct * 64 + ch)) * 32 + y) * 32 + xg * 4;
  float4 v0 = *reinterpret_cast<const float4*>(sp);
  float4 v1 = *reinterpret_cast<const float4*>(sp + 32768);
  tile[ch * 33 + xg * 4 + 0] = v0.x * 10.f;
  tile[ch * 33 + xg * 4 + 1] = v0.y * 10.f;
  tile[ch * 33 + xg * 4 + 2] = v0.z * 10.f;
  tile[ch * 33 + xg * 4 + 3] = v0.w * 10.f;
  tile[(ch + 32) * 33 + xg * 4 + 0] = v1.x * 10.f;
  tile[(ch + 32) * 33 + xg * 4 + 1] = v1.y * 10.f;
  tile[(ch + 32) * 33 + xg * 4 + 2] = v1.z * 10.f;
  tile[(ch + 32) * 33 + xg * 4 + 3] = v1.w * 10.f;
  __syncthreads();
  int xx = t >> 3, ccq = (t & 7) * 8;
  if (xx >= cb && xx < cb + n) {
    __half hv[8];
#pragma unroll
    for (int j = 0; j < 8; ++j) hv[j] = __float2half(tile[(ccq + j) * 33 + xx]);
    __half* dp = dst + ((size_t)((b * 32 + y) * n + (xx - cb))) * 2048 + ct * 64 + ccq;
    *reinterpret_cast<float4*>(dp) = *reinterpret_cast<float4*>(hv);
  }
}

// ============ probs: Tc dlogits -> Tp probs, merging 64 group-partials ============
union H8 { uint4 u; __half2 h[4]; };

__global__ __launch_bounds__(256) void dino_probs(
    const __half* __restrict__ Tc, __half* __restrict__ Tp,
    const float* __restrict__ part_m, const float* __restrict__ part_s) {
  __shared__ float pr[66];              // [0,64): group maxes; 64: M; 65: 1/S
  int bid = blockIdx.x;                 // 3584 texels
  int t = threadIdx.x;
  int p = 0;
#pragma unroll
  for (int q = 1; q < 6; ++q) p += (bid >= g_cumTex[q]) ? 1 : 0;
  int r = bid - g_cumTex[p];
  int n = g_tN[p];
  int by = (n == 2) ? (r >> 1) : (r / 3);
  by = min(max(by, 0), 255);
  int ci = min(max(r - by * n, 0), n - 1);
  int x = g_tCb[p] + ci;                // <= 21 < 32
  int view = (p >= 3) ? 1 : 0;
  int b = by >> 5, y = by & 31;
  int vb = view * 8 + b;

  if (t < 64) {
    float mg = part_m[((size_t)(vb * 64 + t)) * 1024 + y * 32 + x];
    float sg = part_s[((size_t)(vb * 64 + t)) * 1024 + y * 32 + x];
    pr[t] = mg;
    float M = mg;
#pragma unroll
    for (int off = 32; off; off >>= 1) M = fmaxf(M, __shfl_xor(M, off));
    float sv = sg * __expf(mg - M);
#pragma unroll
    for (int off = 32; off; off >>= 1) sv += __shfl_xor(sv, off);
    if (t == 0) { pr[64] = M; pr[65] = 1.f / sv; }
  }
  __syncthreads();
  float off = pr[t >> 2] - pr[64];
  float invS = pr[65];

  int tex = min(g_cumTex[p] + by * n + ci, 3583);
  size_t base = (size_t)tex * 2048 + t * 8;
  H8 hh;
  hh.u = *reinterpret_cast<const uint4*>(Tc + base);
#pragma unroll
  for (int pc = 0; pc < 4; ++pc) {
    float2 f = __half22float2(hh.h[pc]);
    f.x = __expf(f.x + off) * invS;
    f.y = __expf(f.y + off) * invS;
    hh.h[pc] = __floats2half2_rn(f.x, f.y);
  }
  *reinterpret_cast<uint4*>(Tp + base) = hh.u;
}

// ============ main: 1 wave per position, compact layouts ============
__global__ __launch_bounds__(256) void dino_main(
    const __half* __restrict__ Tp,
    const __half* __restrict__ S0, const __half* __restrict__ S1,
    const __half* __restrict__ S2, const __half* __restrict__ S3,
    float* __restrict__ losses) {
  int wid = threadIdx.x >> 6, lane = threadIdx.x & 63;
  int pair = blockIdx.x / 1200;
  int slot = blockIdx.x - pair * 1200;
  PairInfo pi = g_pairs[pair];
  int posInPair = slot * 4 + wid;
  if (posInPair >= pi.per * 8) return;

  unsigned up = (unsigned)posInPair;
  int b = (int)__umulhi(up, pi.magicPer);
  b = min(max(b, 0), 7);
  int r = posInPair - b * pi.per;
  r = min(max(r, 0), pi.per - 1);
  int i = (int)__umulhi((unsigned)r, pi.magicW);
  i = min(max(i, 0), pi.gH - 1);
  int j = r - i * pi.gW;
  j = min(max(j, 0), pi.gW - 1);

  // reference swaps gx/gy: image COLUMN from y-linspace (i), ROW from x-linspace (j)
  float tyy = pi.ty1 + (float)i * (pi.ty2 - pi.ty1) / (float)(pi.gH - 1);
  float txx = pi.tx1 + (float)j * (pi.tx2 - pi.tx1) / (float)(pi.gW - 1);
  float tix = fminf(fmaxf((tyy + 1.0f) * 16.0f - 0.5f, 0.0f), 31.0f);
  float tiy = fminf(fmaxf((txx + 1.0f) * 16.0f - 0.5f, 0.0f), 31.0f);
  int tx0 = (int)tix, ty0 = (int)tiy;
  float wxt = tix - (float)tx0, wyt = tiy - (float)ty0;
  int tx1i = min(tx0 + 1, 31), ty1i = min(ty0 + 1, 31);

  int hs = pi.Hs;
  float hh = 0.5f * (float)hs, hm = (float)(hs - 1);
  float syy = pi.sy1 + (float)i * (pi.sy2 - pi.sy1) / (float)(pi.gH - 1);
  float sxx = pi.sx1 + (float)j * (pi.sx2 - pi.sx1) / (float)(pi.gW - 1);
  float six = fminf(fmaxf((syy + 1.0f) * hh - 0.5f, 0.0f), hm);
  float siy = fminf(fmaxf((sxx + 1.0f) * hh - 0.5f, 0.0f), hm);
  int sx0 = (int)six, sy0 = (int)siy;
  float wxs = six - (float)sx0, wys = siy - (float)sy0;
  int sx1i = min(sx0 + 1, hs - 1), sy1i = min(sy0 + 1, hs - 1);

  const __half* __restrict__ S =
      (pi.v == 0) ? S0 : (pi.v == 1) ? S1 : (pi.v == 2) ? S2 : S3;

  int tc0 = min(max(tx0 - pi.tCb, 0), pi.tN - 1);
  int tc1 = min(max(tx1i - pi.tCb, 0), pi.tN - 1);
  int trow = pi.tOfs + (b * 32 + ty0) * pi.tN;
  int trow1 = pi.tOfs + (b * 32 + ty1i) * pi.tN;
  int toff00 = min(trow + tc0, 3583) * 2048;
  int toff01 = min(trow + tc1, 3583) * 2048;
  int toff10 = min(trow1 + tc0, 3583) * 2048;
  int toff11 = min(trow1 + tc1, 3583) * 2048;
  int sc0 = min(max(sx0 - pi.sCb, 0), pi.sN - 1);
  int sc1 = min(max(sx1i - pi.sCb, 0), pi.sN - 1);
  int soff00 = ((b * hs + sy0) * pi.sN + sc0) * 2048;
  int soff01 = ((b * hs + sy0) * pi.sN + sc1) * 2048;
  int soff10 = ((b * hs + sy1i) * pi.sN + sc0) * 2048;
  int soff11 = ((b * hs + sy1i) * pi.sN + sc1) * 2048;

  __half2 wt00 = __float2half2_rn((1.f - wyt) * (1.f - wxt));
  __half2 wt01 = __float2half2_rn((1.f - wyt) * wxt);
  __half2 wt10 = __float2half2_rn(wyt * (1.f - wxt));
  __half2 wt11 = __float2half2_rn(wyt * wxt);
  __half2 ws00 = __float2half2_rn((1.f - wys) * (1.f - wxs));
  __half2 ws01 = __float2half2_rn((1.f - wys) * wxs);
  __half2 ws10 = __float2half2_rn(wys * (1.f - wxs));
  __half2 ws11 = __float2half2_rn(wys * wxs);

  float sum = 0.f, dot = 0.f;
#pragma unroll
  for (int k = 0; k < 4; ++k) {
    int c0 = (k << 9) + (lane << 3);
    H8 t00, t01, t10, t11, a00, a01, a10, a11;
    t00.u = *reinterpret_cast<const uint4*>(Tp + toff00 + c0);
    t01.u = *reinterpret_cast<const uint4*>(Tp + toff01 + c0);
    t10.u = *reinterpret_cast<const uint4*>(Tp + toff10 + c0);
    t11.u = *reinterpret_cast<const uint4*>(Tp + toff11 + c0);
    a00.u = *reinterpret_cast<const uint4*>(S + soff00 + c0);
    a01.u = *reinterpret_cast<const uint4*>(S + soff01 + c0);
    a10.u = *reinterpret_cast<const uint4*>(S + soff10 + c0);
    a11.u = *reinterpret_cast<const uint4*>(S + soff11 + c0);
#pragma unroll
    for (int p = 0; p < 4; ++p) {
      __half2 tc2 = __hmul2(wt00, t00.h[p]);
      tc2 = __hfma2(wt01, t01.h[p], tc2);
      tc2 = __hfma2(wt10, t10.h[p], tc2);
      tc2 = __hfma2(wt11, t11.h[p], tc2);
      __half2 sc2 = __hmul2(ws00, a00.h[p]);
      sc2 = __hfma2(ws01, a01.h[p], sc2);
      sc2 = __hfma2(ws10, a10.h[p], sc2);
      sc2 = __hfma2(ws11, a11.h[p], sc2);
      dot = fdot2f(tc2, sc2, dot);
      float2 scf = __half22float2(sc2);
      sum += __expf(scf.x);
      sum += __expf(scf.y);
    }
  }
#pragma unroll
  for (int off = 32; off; off >>= 1) {
    sum += __shfl_down(sum, off);
    dot += __shfl_down(dot, off);
  }
  if (lane == 0) losses[pi.base + posInPair] = logf(sum) - dot;
}

// ============ final mean ============
__global__ __launch_bounds__(1024) void dino_reduce(const float* __restrict__ losses,
                                                    float* __restrict__ out) {
  __shared__ double sd[1024];
  int t = threadIdx.x;
  double a = 0.0;
  for (int i4 = t; i4 < 6672; i4 += 1024) {
    float4 v = *reinterpret_cast<const float4*>(losses + i4 * 4);
    a += (double)v.x + (double)v.y + (double)v.z + (double)v.w;
  }
  sd[t] = a;
  __syncthreads();
  for (int off = 512; off; off >>= 1) {
    if (t < off) sd[t] += sd[t + off];
    __syncthreads();
  }
  if (t == 0) out[0] = (float)(sd[0] / (double)NPOS);
}

extern "C" void kernel_launch(void* const* d_in, const int* in_sizes, int n_in,
                              void* d_out, int out_size, void* d_ws, size_t ws_size,
                              hipStream_t stream) {
  const float* sg0 = (const float*)d_in[0];
  const float* sg1 = (const float*)d_in[1];
  const float* sl0 = (const float*)d_in[2];
  const float* sl1 = (const float*)d_in[3];
  const float* tg0 = (const float*)d_in[4];
  const float* tg1 = (const float*)d_in[5];
  const float* cen = (const float*)d_in[6];
  const int* epoch = (const int*)d_in[7];
  float* out = (float*)d_out;
  char* w = (char*)d_ws;

  // ws layout (bytes), total 95,682,560 (>=143.9 MB proven available in round 1)
  const size_t OFF_LOSS= 131072;       // 106752 (pad to 262144)
  const size_t OFF_PM  = 262144;       // 4 MB  (16 vb x 64 cg x 1024 texels f32)
  const size_t OFF_PS  = 4456448;      // 4 MB
  const size_t OFF_TC  = 8650752;      // 14,680,064 (3584 x 2048 fp16 dlogits)
  const size_t OFF_TP  = 23330816;     // 14,680,064 (3584 x 2048 fp16 probs)
  const size_t OFF_SG0 = 38010880;     // 25,165,824 (8*32*24*2048 fp16)
  const size_t OFF_SG1 = 63176704;     // 23,068,672 (8*32*22*2048 fp16)
  const size_t OFF_SL0 = 86245376;     // 4,718,592
  const size_t OFF_SL1 = 90963968;     // 4,718,592

  float* losses = (float*)(w + OFF_LOSS);
  float* part_m = (float*)(w + OFF_PM);
  float* part_s = (float*)(w + OFF_PS);
  __half* Tc  = (__half*)(w + OFF_TC);
  __half* Tp  = (__half*)(w + OFF_TP);
  __half* Sg0 = (__half*)(w + OFF_SG0);
  __half* Sg1 = (__half*)(w + OFF_SG1);
  __half* Sl0 = (__half*)(w + OFF_SL0);
  __half* Sl1 = (__half*)(w + OFF_SL1);

  // phase1 grid: stats[0,1024) | t12[1024,3072) | t32[3072,16384)
  dino_phase1<<<16384, 256, 0, stream>>>(tg0, tg1, cen, epoch, part_m, part_s, Tc,
                                         sl0, sl1, Sl0, Sl1, sg0, sg1, Sg0, Sg1);
  dino_probs<<<3584, 256, 0, stream>>>(Tc, Tp, part_m, part_s);
  dino_main<<<7200, 256, 0, stream>>>(Tp, Sg0, Sg1, Sl0, Sl1, losses);
  dino_reduce<<<1, 1024, 0, stream>>>(losses, out);
}

// Round 9
// 142.183 us; speedup vs baseline: 1.6326x; 1.6326x over previous
//
#include <hip/hip_runtime.h>
#include <hip/hip_fp16.h>

#define NPOS 26688

struct PairInfo {
  int iq, v, Hs, gH, gW, base, per;
  unsigned magicPer, magicW;
  int tOfs, tN, tCb;     // teacher compact: texel offset, #cols, col base
  int sN, sCb;           // student compact: #cols, col base (locals: 12,0)
  float tx1, tx2, ty1, ty2;
  float sx1, sx2, sy1, sy2;
};

// magic = ceil(2^32/d); error-term checked for all used ranges
__constant__ PairInfo g_pairs[6] = {
  {0,1,32,25,24,    0,600, 7158279u,178956971u,    0,2, 7, 22,5, -0.80f,0.70f,-0.500f,-0.475f,  -0.90f,0.60f,-0.60f,0.60f},
  {0,2,12,25,24, 4800,600, 7158279u,178956971u,  512,2,17, 12,0, -0.75f,0.75f, 0.100f, 0.125f,  -0.80f,0.80f,-0.80f,0.80f},
  {0,3,12,22,24, 9600,528, 8134408u,178956971u, 1024,2,12, 12,0, -0.60f,0.90f,-0.200f,-0.178f,  -0.70f,0.90f,-0.90f,0.70f},
  {1,0,32,22,24,13824,528, 8134408u,178956971u, 1536,2,20, 24,7, -0.70f,0.80f, 0.300f, 0.322f,  -0.85f,0.65f,-0.50f,0.90f},
  {1,2,12,24,22,18048,528, 8134408u,195225787u, 2048,3,13, 12,0, -0.90f,0.50f,-0.100f,-0.076f,  -0.60f,0.95f,-0.95f,0.60f},
  {1,3,12,24,23,22272,552, 7780739u,186737709u, 2816,3,18, 12,0, -0.50f,0.95f, 0.200f, 0.224f,  -0.90f,0.90f,-0.40f,0.95f},
};

// sampled-column x -> LDS staging slot (-1 = not sampled)
__constant__ int g_ux[2][32] = {
  {-1,-1,-1,-1,-1,-1,-1, 0, 1,-1,-1,-1, 2, 3,-1,-1,-1, 4, 5,-1,-1,-1,-1,-1,-1,-1,-1,-1,-1,-1,-1,-1},
  {-1,-1,-1,-1,-1,-1,-1,-1,-1,-1,-1,-1,-1, 0, 1, 2,-1,-1, 3, 4, 5, 6,-1,-1,-1,-1,-1,-1,-1,-1,-1,-1},
};
// write-out entries: slot -> tex = base + (b*32+y)*stride
// (derived from the g_tent tables validated in rounds 5-8; view1 col20 feeds 2 pairs)
__constant__ int g_weSlot[2][8] = {{0,1,2,3,4,5,0,0},{0,1,2,3,4,5,5,6}};
__constant__ int g_weBase[2][8] = {{0,1,1024,1025,512,513,0,0},
                                   {2048,2049,2050,2816,2817,2818,1536,1537}};
__constant__ int g_weStr[2][8]  = {{2,2,2,2,2,2,2,2},{3,3,3,3,3,3,2,2}};
__constant__ int g_weN[2] = {6, 8};

__device__ inline float get_invtemp(const int* __restrict__ ep) {
  int e = ep[0];
  e = e < 0 ? 0 : (e > 99 ? 99 : e);
  float temp = (e < 30) ? (0.04f + (float)e * (0.03f / 29.0f)) : 0.07f;
  return 1.0f / temp;
}

typedef _Float16 hv2 __attribute__((ext_vector_type(2)));
__device__ inline float fdot2f(__half2 a, __half2 b, float c) {
#if defined(__has_builtin)
#if __has_builtin(__builtin_amdgcn_fdot2)
  return __builtin_amdgcn_fdot2(*reinterpret_cast<hv2*>(&a),
                                *reinterpret_cast<hv2*>(&b), c, false);
#else
  float2 af = __half22float2(a), bf = __half22float2(b);
  return fmaf(af.x, bf.x, fmaf(af.y, bf.y, c));
#endif
#else
  float2 af = __half22float2(a), bf = __half22float2(b);
  return fmaf(af.x, bf.x, fmaf(af.y, bf.y, c));
#endif
}

// ===== phase1 (all-streaming transposes):
//   teacher Tc [0,2048) | student-global [2048,4096) | student-local [4096,6144)
__global__ __launch_bounds__(256) void dino_phase1(
    const float* __restrict__ tg0, const float* __restrict__ tg1,
    float* __restrict__ Tcf,
    const float* __restrict__ sg0, const float* __restrict__ sg1,
    __half* __restrict__ Sg0, __half* __restrict__ Sg1,
    const float* __restrict__ sl0, const float* __restrict__ sl1,
    __half* __restrict__ Sl0, __half* __restrict__ Sl1) {
  __shared__ float smem[5700];          // 22.8 KB, aliased per branch
  int bid = blockIdx.x;
  int t = threadIdx.x;

  if (bid < 2048) {
    // ---- teacher: (view,b,cg16) streams 64KB, stages sampled cols, writes Tc f32 ----
    int cg = bid & 127;
    int b = (bid >> 7) & 7;
    int view = bid >> 10;               // [0,2)
    const float* __restrict__ src = view ? tg1 : tg0;
    const float* base = src + ((size_t)(b * 2048 + cg * 16)) * 1024;
    // LDS: [slot][y*17 + c], slot*544
#pragma unroll
    for (int k = 0; k < 16; ++k) {
      int idx = k * 256 + t;
      int c = idx >> 8, p4 = idx & 255;
      int y = p4 >> 3, x0 = (p4 & 7) * 4;
      float4 v = *reinterpret_cast<const float4*>(base + (size_t)c * 1024 + p4 * 4);
      int s0 = g_ux[view][x0],     s1 = g_ux[view][x0 + 1];
      int s2 = g_ux[view][x0 + 2], s3 = g_ux[view][x0 + 3];
      if (s0 >= 0) smem[s0 * 544 + y * 17 + c] = v.x;
      if (s1 >= 0) smem[s1 * 544 + y * 17 + c] = v.y;
      if (s2 >= 0) smem[s2 * 544 + y * 17 + c] = v.z;
      if (s3 >= 0) smem[s3 * 544 + y * 17 + c] = v.w;
    }
    __syncthreads();
    int nw = g_weN[view];
    if (t < nw * 32) {
      int e = t >> 5, y = t & 31;
      int slot = g_weSlot[view][e];
      int tex = g_weBase[view][e] + (b * 32 + y) * g_weStr[view][e];
      tex = min(max(tex, 0), 3583);
      float arr[16];
#pragma unroll
      for (int c = 0; c < 16; ++c) arr[c] = smem[slot * 544 + y * 17 + c];
      float* dp = Tcf + (size_t)tex * 2048 + cg * 16;
#pragma unroll
      for (int q = 0; q < 4; ++q)
        *reinterpret_cast<float4*>(dp + q * 4) =
            make_float4(arr[4 * q], arr[4 * q + 1], arr[4 * q + 2], arr[4 * q + 3]);
    }
    return;
  }

  if (bid < 4096) {
    // ---- student-global: (which,b,cg16) streams 64KB, stages window fp16 ----
    int lb = bid - 2048;
    int cg = lb & 127;
    int b = (lb >> 7) & 7;
    int which = lb >> 10;
    const float* __restrict__ src = which ? sg1 : sg0;
    __half* __restrict__ dst = which ? Sg1 : Sg0;
    int cb = which ? 5 : 7;
    int n = which ? 22 : 24;
    unsigned magicN = which ? 195225787u : 178956971u;
    const float* base = src + ((size_t)(b * 2048 + cg * 16)) * 1024;
    __half* hlds = reinterpret_cast<__half*>(smem);   // [pos*18 + c]
#pragma unroll
    for (int k = 0; k < 16; ++k) {
      int idx = k * 256 + t;
      int c = idx >> 8, p4 = idx & 255;
      int y = p4 >> 3, x0 = (p4 & 7) * 4;
      float4 v = *reinterpret_cast<const float4*>(base + (size_t)c * 1024 + p4 * 4);
      if (y >= 1 && y <= 26) {
        int rb = (y - 1) * n - cb;
#pragma unroll
        for (int q = 0; q < 4; ++q) {
          int x = x0 + q;
          if (x >= cb && x < cb + n) {
            float val = (q == 0) ? v.x : (q == 1) ? v.y : (q == 2) ? v.z : v.w;
            hlds[(rb + x) * 18 + c] = __float2half(val * 10.f);
          }
        }
      }
    }
    __syncthreads();
    int total = 26 * n;                 // 624 or 572
    const unsigned* hw = reinterpret_cast<const unsigned*>(smem);
#pragma unroll
    for (int k2 = 0; k2 < 3; ++k2) {
      int u = t + 256 * k2;
      if (u < total) {
        int yy = (int)__umulhi((unsigned)u, magicN);   // u / n
        int cx = u - yy * n;
        int y = yy + 1;
        unsigned r[8];
#pragma unroll
        for (int q = 0; q < 8; ++q) r[q] = hw[u * 9 + q];
        unsigned* dp = reinterpret_cast<unsigned*>(
            dst + ((size_t)((b * 32 + y) * n + cx)) * 2048 + cg * 16);
        *reinterpret_cast<uint4*>(dp) = make_uint4(r[0], r[1], r[2], r[3]);
        *reinterpret_cast<uint4*>(dp + 4) = make_uint4(r[4], r[5], r[6], r[7]);
      }
    }
    return;
  }

  // ---- student 12x12 transpose, 16 ch/block: 2048 = v(2)*b(8)*ct(128) ----
  float* tile = smem;                   // 16*145 = 2320
  int lb = bid - 4096;
  int ct = lb & 127;
  int g = lb >> 7;
  int b = g & 7;
  int vv = g >> 3;
  const float* __restrict__ src = vv ? sl1 : sl0;
  __half* __restrict__ dst = vv ? Sl1 : Sl0;
  const float* sp = src + ((size_t)(b * 2048 + ct * 16)) * 144;
#pragma unroll
  for (int k = 0; k < 9; ++k) {         // 2304 contiguous floats in
    int idx = t + 256 * k;
    int c = idx / 144;
    int yx = idx - c * 144;
    tile[c * 145 + yx] = sp[idx] * 10.f;
  }
  __syncthreads();
  __half* dp = dst + ((size_t)(b * 144)) * 2048 + ct * 16;
#pragma unroll
  for (int k = 0; k < 2; ++k) {         // 288 float4 chunks out
    int u = t + 256 * k;
    if (u < 288) {
      int yx = u >> 1, q8 = (u & 1) * 8;
      __half hv[8];
#pragma unroll
      for (int j = 0; j < 8; ++j) hv[j] = __float2half(tile[(q8 + j) * 145 + yx]);
      *reinterpret_cast<float4*>(dp + (size_t)yx * 2048 + q8) =
          *reinterpret_cast<float4*>(hv);
    }
  }
}

// ===== probs: per-texel full softmax from raw Tc (f32) -> Tp (fp16) =====
__global__ __launch_bounds__(256) void dino_probs(
    const float* __restrict__ Tcf, __half* __restrict__ Tp,
    const float* __restrict__ cen, const int* __restrict__ ep) {
  __shared__ float rm[4], rs[4];
  int tex = blockIdx.x;                 // [0,3584)
  int t = threadIdx.x;
  int lane = t & 63, w = t >> 6;
  float invtemp = get_invtemp(ep);

  const float* cp = Tcf + (size_t)tex * 2048 + t * 8;
  float4 v0 = *reinterpret_cast<const float4*>(cp);
  float4 v1 = *reinterpret_cast<const float4*>(cp + 4);
  float4 c0 = *reinterpret_cast<const float4*>(cen + t * 8);
  float4 c1 = *reinterpret_cast<const float4*>(cen + t * 8 + 4);
  float lg[8];
  lg[0] = (v0.x - c0.x) * invtemp; lg[1] = (v0.y - c0.y) * invtemp;
  lg[2] = (v0.z - c0.z) * invtemp; lg[3] = (v0.w - c0.w) * invtemp;
  lg[4] = (v1.x - c1.x) * invtemp; lg[5] = (v1.y - c1.y) * invtemp;
  lg[6] = (v1.z - c1.z) * invtemp; lg[7] = (v1.w - c1.w) * invtemp;

  float m = lg[0];
#pragma unroll
  for (int q = 1; q < 8; ++q) m = fmaxf(m, lg[q]);
#pragma unroll
  for (int off = 32; off; off >>= 1) m = fmaxf(m, __shfl_xor(m, off));
  if (lane == 0) rm[w] = m;
  __syncthreads();
  float M = fmaxf(fmaxf(rm[0], rm[1]), fmaxf(rm[2], rm[3]));

  float e[8];
  float s = 0.f;
#pragma unroll
  for (int q = 0; q < 8; ++q) { e[q] = __expf(lg[q] - M); s += e[q]; }
#pragma unroll
  for (int off = 32; off; off >>= 1) s += __shfl_xor(s, off);
  if (lane == 0) rs[w] = s;
  __syncthreads();
  float invS = 1.f / (rs[0] + rs[1] + rs[2] + rs[3]);

  __half o[8];
#pragma unroll
  for (int q = 0; q < 8; ++q) o[q] = __float2half(e[q] * invS);
  *reinterpret_cast<uint4*>(Tp + (size_t)tex * 2048 + t * 8) =
      *reinterpret_cast<uint4*>(o);
}

// ===== main: 1 wave per position, compact layouts (unchanged, validated) =====
union H8 { uint4 u; __half2 h[4]; };

__global__ __launch_bounds__(256) void dino_main(
    const __half* __restrict__ Tp,
    const __half* __restrict__ S0, const __half* __restrict__ S1,
    const __half* __restrict__ S2, const __half* __restrict__ S3,
    float* __restrict__ losses) {
  int wid = threadIdx.x >> 6, lane = threadIdx.x & 63;
  int pair = blockIdx.x / 1200;
  int slot = blockIdx.x - pair * 1200;
  PairInfo pi = g_pairs[pair];
  int posInPair = slot * 4 + wid;
  if (posInPair >= pi.per * 8) return;

  unsigned up = (unsigned)posInPair;
  int b = (int)__umulhi(up, pi.magicPer);
  b = min(max(b, 0), 7);
  int r = posInPair - b * pi.per;
  r = min(max(r, 0), pi.per - 1);
  int i = (int)__umulhi((unsigned)r, pi.magicW);
  i = min(max(i, 0), pi.gH - 1);
  int j = r - i * pi.gW;
  j = min(max(j, 0), pi.gW - 1);

  // reference swaps gx/gy: image COLUMN from y-linspace (i), ROW from x-linspace (j)
  float tyy = pi.ty1 + (float)i * (pi.ty2 - pi.ty1) / (float)(pi.gH - 1);
  float txx = pi.tx1 + (float)j * (pi.tx2 - pi.tx1) / (float)(pi.gW - 1);
  float tix = fminf(fmaxf((tyy + 1.0f) * 16.0f - 0.5f, 0.0f), 31.0f);
  float tiy = fminf(fmaxf((txx + 1.0f) * 16.0f - 0.5f, 0.0f), 31.0f);
  int tx0 = (int)tix, ty0 = (int)tiy;
  float wxt = tix - (float)tx0, wyt = tiy - (float)ty0;
  int tx1i = min(tx0 + 1, 31), ty1i = min(ty0 + 1, 31);

  int hs = pi.Hs;
  float hh = 0.5f * (float)hs, hm = (float)(hs - 1);
  float syy = pi.sy1 + (float)i * (pi.sy2 - pi.sy1) / (float)(pi.gH - 1);
  float sxx = pi.sx1 + (float)j * (pi.sx2 - pi.sx1) / (float)(pi.gW - 1);
  float six = fminf(fmaxf((syy + 1.0f) * hh - 0.5f, 0.0f), hm);
  float siy = fminf(fmaxf((sxx + 1.0f) * hh - 0.5f, 0.0f), hm);
  int sx0 = (int)six, sy0 = (int)siy;
  float wxs = six - (float)sx0, wys = siy - (float)sy0;
  int sx1i = min(sx0 + 1, hs - 1), sy1i = min(sy0 + 1, hs - 1);

  const __half* __restrict__ S =
      (pi.v == 0) ? S0 : (pi.v == 1) ? S1 : (pi.v == 2) ? S2 : S3;

  int tc0 = min(max(tx0 - pi.tCb, 0), pi.tN - 1);
  int tc1 = min(max(tx1i - pi.tCb, 0), pi.tN - 1);
  int trow = pi.tOfs + (b * 32 + ty0) * pi.tN;
  int trow1 = pi.tOfs + (b * 32 + ty1i) * pi.tN;
  int toff00 = min(trow + tc0, 3583) * 2048;
  int toff01 = min(trow + tc1, 3583) * 2048;
  int toff10 = min(trow1 + tc0, 3583) * 2048;
  int toff11 = min(trow1 + tc1, 3583) * 2048;
  int sc0 = min(max(sx0 - pi.sCb, 0), pi.sN - 1);
  int sc1 = min(max(sx1i - pi.sCb, 0), pi.sN - 1);
  int soff00 = ((b * hs + sy0) * pi.sN + sc0) * 2048;
  int soff01 = ((b * hs + sy0) * pi.sN + sc1) * 2048;
  int soff10 = ((b * hs + sy1i) * pi.sN + sc0) * 2048;
  int soff11 = ((b * hs + sy1i) * pi.sN + sc1) * 2048;

  __half2 wt00 = __float2half2_rn((1.f - wyt) * (1.f - wxt));
  __half2 wt01 = __float2half2_rn((1.f - wyt) * wxt);
  __half2 wt10 = __float2half2_rn(wyt * (1.f - wxt));
  __half2 wt11 = __float2half2_rn(wyt * wxt);
  __half2 ws00 = __float2half2_rn((1.f - wys) * (1.f - wxs));
  __half2 ws01 = __float2half2_rn((1.f - wys) * wxs);
  __half2 ws10 = __float2half2_rn(wys * (1.f - wxs));
  __half2 ws11 = __float2half2_rn(wys * wxs);

  float sum = 0.f, dot = 0.f;
#pragma unroll
  for (int k = 0; k < 4; ++k) {
    int c0 = (k << 9) + (lane << 3);
    H8 t00, t01, t10, t11, a00, a01, a10, a11;
    t00.u = *reinterpret_cast<const uint4*>(Tp + toff00 + c0);
    t01.u = *reinterpret_cast<const uint4*>(Tp + toff01 + c0);
    t10.u = *reinterpret_cast<const uint4*>(Tp + toff10 + c0);
    t11.u = *reinterpret_cast<const uint4*>(Tp + toff11 + c0);
    a00.u = *reinterpret_cast<const uint4*>(S + soff00 + c0);
    a01.u = *reinterpret_cast<const uint4*>(S + soff01 + c0);
    a10.u = *reinterpret_cast<const uint4*>(S + soff10 + c0);
    a11.u = *reinterpret_cast<const uint4*>(S + soff11 + c0);
#pragma unroll
    for (int p = 0; p < 4; ++p) {
      __half2 tc2 = __hmul2(wt00, t00.h[p]);
      tc2 = __hfma2(wt01, t01.h[p], tc2);
      tc2 = __hfma2(wt10, t10.h[p], tc2);
      tc2 = __hfma2(wt11, t11.h[p], tc2);
      __half2 sc2 = __hmul2(ws00, a00.h[p]);
      sc2 = __hfma2(ws01, a01.h[p], sc2);
      sc2 = __hfma2(ws10, a10.h[p], sc2);
      sc2 = __hfma2(ws11, a11.h[p], sc2);
      dot = fdot2f(tc2, sc2, dot);
      float2 scf = __half22float2(sc2);
      sum += __expf(scf.x);
      sum += __expf(scf.y);
    }
  }
#pragma unroll
  for (int off = 32; off; off >>= 1) {
    sum += __shfl_down(sum, off);
    dot += __shfl_down(dot, off);
  }
  if (lane == 0) losses[pi.base + posInPair] = logf(sum) - dot;
}

// ===== final mean =====
__global__ __launch_bounds__(1024) void dino_reduce(const float* __restrict__ losses,
                                                    float* __restrict__ out) {
  __shared__ double sd[1024];
  int t = threadIdx.x;
  double a = 0.0;
  for (int i4 = t; i4 < 6672; i4 += 1024) {
    float4 v = *reinterpret_cast<const float4*>(losses + i4 * 4);
    a += (double)v.x + (double)v.y + (double)v.z + (double)v.w;
  }
  sd[t] = a;
  __syncthreads();
  for (int off = 512; off; off >>= 1) {
    if (t < off) sd[t] += sd[t + off];
    __syncthreads();
  }
  if (t == 0) out[0] = (float)(sd[0] / (double)NPOS);
}

extern "C" void kernel_launch(void* const* d_in, const int* in_sizes, int n_in,
                              void* d_out, int out_size, void* d_ws, size_t ws_size,
                              hipStream_t stream) {
  const float* sg0 = (const float*)d_in[0];
  const float* sg1 = (const float*)d_in[1];
  const float* sl0 = (const float*)d_in[2];
  const float* sl1 = (const float*)d_in[3];
  const float* tg0 = (const float*)d_in[4];
  const float* tg1 = (const float*)d_in[5];
  const float* cen = (const float*)d_in[6];
  const int* epoch = (const int*)d_in[7];
  float* out = (float*)d_out;
  char* w = (char*)d_ws;

  // ws layout (bytes), total 101,974,016 (>=143.9 MB proven available in round 1)
  const size_t OFF_LOSS = 131072;       // 106752 (pad to 262144)
  const size_t OFF_TCF  = 262144;       // 29,360,128 (3584 x 2048 f32 raw teacher)
  const size_t OFF_TP   = 29622272;     // 14,680,064 (3584 x 2048 fp16 probs)
  const size_t OFF_SG0  = 44302336;     // 25,165,824 (8*32*24*2048 fp16)
  const size_t OFF_SG1  = 69468160;     // 23,068,672 (8*32*22*2048 fp16)
  const size_t OFF_SL0  = 92536832;     // 4,718,592
  const size_t OFF_SL1  = 97255424;     // 4,718,592

  float* losses = (float*)(w + OFF_LOSS);
  float* Tcf = (float*)(w + OFF_TCF);
  __half* Tp  = (__half*)(w + OFF_TP);
  __half* Sg0 = (__half*)(w + OFF_SG0);
  __half* Sg1 = (__half*)(w + OFF_SG1);
  __half* Sl0 = (__half*)(w + OFF_SL0);
  __half* Sl1 = (__half*)(w + OFF_SL1);

  // phase1 grid: teacher[0,2048) | sg[2048,4096) | sl[4096,6144)
  dino_phase1<<<6144, 256, 0, stream>>>(tg0, tg1, Tcf, sg0, sg1, Sg0, Sg1,
                                        sl0, sl1, Sl0, Sl1);
  dino_probs<<<3584, 256, 0, stream>>>(Tcf, Tp, cen, epoch);
  dino_main<<<7200, 256, 0, stream>>>(Tp, Sg0, Sg1, Sl0, Sl1, losses);
  dino_reduce<<<1, 1024, 0, stream>>>(losses, out);
}

// Round 11
// 122.035 us; speedup vs baseline: 1.9022x; 1.1651x over previous
//
#include <hip/hip_runtime.h>
#include <hip/hip_fp16.h>

#define NPOS 26688

struct PairInfo {
  int iq, v, Hs, gH, gW, base, per;
  unsigned magicPer, magicW;
  int tOfs, tN, tCb;     // teacher compact: texel offset, #cols, col base
  int sN, sCb;           // student compact: #cols, col base (locals: 12,0)
  float tx1, tx2, ty1, ty2;
  float sx1, sx2, sy1, sy2;
};

// magic = ceil(2^32/d); error-term checked for all used ranges
__constant__ PairInfo g_pairs[6] = {
  {0,1,32,25,24,    0,600, 7158279u,178956971u,    0,2, 7, 22,5, -0.80f,0.70f,-0.500f,-0.475f,  -0.90f,0.60f,-0.60f,0.60f},
  {0,2,12,25,24, 4800,600, 7158279u,178956971u,  512,2,17, 12,0, -0.75f,0.75f, 0.100f, 0.125f,  -0.80f,0.80f,-0.80f,0.80f},
  {0,3,12,22,24, 9600,528, 8134408u,178956971u, 1024,2,12, 12,0, -0.60f,0.90f,-0.200f,-0.178f,  -0.70f,0.90f,-0.90f,0.70f},
  {1,0,32,22,24,13824,528, 8134408u,178956971u, 1536,2,20, 24,7, -0.70f,0.80f, 0.300f, 0.322f,  -0.85f,0.65f,-0.50f,0.90f},
  {1,2,12,24,22,18048,528, 8134408u,195225787u, 2048,3,13, 12,0, -0.90f,0.50f,-0.100f,-0.076f,  -0.60f,0.95f,-0.95f,0.60f},
  {1,3,12,24,23,22272,552, 7780739u,186737709u, 2816,3,18, 12,0, -0.50f,0.95f, 0.200f, 0.224f,  -0.90f,0.90f,-0.40f,0.95f},
};

// sampled-column x -> LDS staging slot (-1 = not sampled)
__constant__ int g_ux[2][32] = {
  {-1,-1,-1,-1,-1,-1,-1, 0, 1,-1,-1,-1, 2, 3,-1,-1,-1, 4, 5,-1,-1,-1,-1,-1,-1,-1,-1,-1,-1,-1,-1,-1},
  {-1,-1,-1,-1,-1,-1,-1,-1,-1,-1,-1,-1,-1, 0, 1, 2,-1,-1, 3, 4, 5, 6,-1,-1,-1,-1,-1,-1,-1,-1,-1,-1},
};
// write-out entries: slot -> tex = base + (b*32+y)*stride (validated r5-r9)
__constant__ int g_weSlot[2][8] = {{0,1,2,3,4,5,0,0},{0,1,2,3,4,5,5,6}};
__constant__ int g_weBase[2][8] = {{0,1,1024,1025,512,513,0,0},
                                   {2048,2049,2050,2816,2817,2818,1536,1537}};
__constant__ int g_weStr[2][8]  = {{2,2,2,2,2,2,2,2},{3,3,3,3,3,3,2,2}};
__constant__ int g_weN[2] = {6, 8};

__device__ inline float get_invtemp(const int* __restrict__ ep) {
  int e = ep[0];
  e = e < 0 ? 0 : (e > 99 ? 99 : e);
  float temp = (e < 30) ? (0.04f + (float)e * (0.03f / 29.0f)) : 0.07f;
  return 1.0f / temp;
}

typedef _Float16 hv2 __attribute__((ext_vector_type(2)));
__device__ inline float fdot2f(__half2 a, __half2 b, float c) {
#if defined(__has_builtin)
#if __has_builtin(__builtin_amdgcn_fdot2)
  return __builtin_amdgcn_fdot2(*reinterpret_cast<hv2*>(&a),
                                *reinterpret_cast<hv2*>(&b), c, false);
#else
  float2 af = __half22float2(a), bf = __half22float2(b);
  return fmaf(af.x, bf.x, fmaf(af.y, bf.y, c));
#endif
#else
  float2 af = __half22float2(a), bf = __half22float2(b);
  return fmaf(af.x, bf.x, fmaf(af.y, bf.y, c));
#endif
}

// ===== phase1: teacher[0,1024) | student-global[1024,3072) | student-local[3072,4096)
// All branches: streaming >=1KB/wave reads, 64B-granule coalesced writes, fp16 LDS.
__global__ __launch_bounds__(256) void dino_phase1(
    const float* __restrict__ tg0, const float* __restrict__ tg1,
    __half* __restrict__ Tch,
    const float* __restrict__ sg0, const float* __restrict__ sg1,
    __half* __restrict__ Sg0, __half* __restrict__ Sg1,
    const float* __restrict__ sl0, const float* __restrict__ sl1,
    __half* __restrict__ Sl0, __half* __restrict__ Sl1) {
  __shared__ __half smem_h[11232];      // 22464 B max (sg branch)
  int bid = blockIdx.x;
  int t = threadIdx.x;

  if (bid < 1024) {
    // ---- teacher: (view,b,cg32); stage sampled cols fp16; 64B writes ----
    int cg = bid & 63;
    int b = (bid >> 6) & 7;
    int view = bid >> 9;
    const float* __restrict__ src = view ? tg1 : tg0;
    const float* base = src + ((size_t)(b * 2048 + cg * 32)) * 1024;
    int y = t >> 3, x0 = (t & 7) * 4;
    int s0 = g_ux[view][x0], s1 = g_ux[view][x0 + 1];
    int s2 = g_ux[view][x0 + 2], s3 = g_ux[view][x0 + 3];
    int smax = max(max(s0, s1), max(s2, s3));
    if (smax >= 0) {                    // only x-blocks containing sampled cols load
#pragma unroll 8
      for (int c = 0; c < 32; ++c) {
        float4 v = *reinterpret_cast<const float4*>(base + (size_t)c * 1024 + t * 4);
        if (s0 >= 0) smem_h[s0 * 1280 + y * 40 + c] = __float2half(v.x);
        if (s1 >= 0) smem_h[s1 * 1280 + y * 40 + c] = __float2half(v.y);
        if (s2 >= 0) smem_h[s2 * 1280 + y * 40 + c] = __float2half(v.z);
        if (s3 >= 0) smem_h[s3 * 1280 + y * 40 + c] = __float2half(v.w);
      }
    }
    __syncthreads();
    int tasks = g_weN[view] * 128;      // e x 32y x 4lq
#pragma unroll
    for (int it = 0; it < 4; ++it) {
      int u = t + it * 256;
      if (u < tasks) {
        int e = u >> 7, rem = u & 127, yy = rem >> 2, lq = rem & 3;
        int slot = g_weSlot[view][e];
        int tex = g_weBase[view][e] + (b * 32 + yy) * g_weStr[view][e];
        tex = min(max(tex, 0), 3583);
        uint4 val = *reinterpret_cast<const uint4*>(&smem_h[slot * 1280 + yy * 40 + lq * 8]);
        *reinterpret_cast<uint4*>(Tch + (size_t)tex * 2048 + cg * 32 + lq * 8) = val;
      }
    }
    return;
  }

  if (bid < 3072) {
    // ---- student-global: (which,b,half13,cg32); rows 1..26 only; 64B writes ----
    int lb = bid - 1024;
    int cg = lb & 63;
    int half = (lb >> 6) & 1;
    int b = (lb >> 7) & 7;
    int which = lb >> 10;
    const float* __restrict__ src = which ? sg1 : sg0;
    __half* __restrict__ dst = which ? Sg1 : Sg0;
    int cb = which ? 5 : 7;
    int n = which ? 22 : 24;
    unsigned magicN = which ? 195225787u : 178956971u;
    int y0 = 1 + half * 13;
    const float* pb = src + ((size_t)(b * 2048 + cg * 32)) * 1024 + y0 * 32;
#pragma unroll 4
    for (int it = 0; it < 13; ++it) {   // 3328 float4 tasks: 32ch x 104
      int u2 = t + it * 256;
      int c = u2 / 104;
      int rem = u2 - c * 104;
      int x0 = (rem & 7) * 4;
      if (x0 + 3 >= cb && x0 < cb + n) {
        float4 v = *reinterpret_cast<const float4*>(pb + (size_t)c * 1024 + rem * 4);
        int pbase = (rem >> 3) * n - cb;
        if (x0 >= cb && x0 < cb + n)         smem_h[(pbase + x0) * 36 + c] = __float2half(v.x * 10.f);
        if (x0 + 1 >= cb && x0 + 1 < cb + n) smem_h[(pbase + x0 + 1) * 36 + c] = __float2half(v.y * 10.f);
        if (x0 + 2 >= cb && x0 + 2 < cb + n) smem_h[(pbase + x0 + 2) * 36 + c] = __float2half(v.z * 10.f);
        if (x0 + 3 >= cb && x0 + 3 < cb + n) smem_h[(pbase + x0 + 3) * 36 + c] = __float2half(v.w * 10.f);
      }
    }
    __syncthreads();
    int tasks = 13 * n * 4;             // 1248 / 1144
#pragma unroll
    for (int it = 0; it < 5; ++it) {
      int u = t + it * 256;
      if (u < tasks) {
        int pos = u >> 2, lq = u & 3;
        int yr = (int)__umulhi((unsigned)pos, magicN);   // pos / n
        int cx = pos - yr * n;
        int yy = y0 + yr;
        uint2 a = *reinterpret_cast<const uint2*>(&smem_h[pos * 36 + lq * 8]);
        uint2 b2 = *reinterpret_cast<const uint2*>(&smem_h[pos * 36 + lq * 8 + 4]);
        *reinterpret_cast<uint4*>(dst + ((size_t)((b * 32 + yy) * n + cx)) * 2048 +
                                  cg * 32 + lq * 8) = make_uint4(a.x, a.y, b2.x, b2.y);
      }
    }
    return;
  }

  // ---- student-local: (v,b,cg32); contiguous read; 64B writes ----
  int lb = bid - 3072;
  int cg = lb & 63;
  int b = (lb >> 6) & 7;
  int vv = lb >> 9;
  const float* __restrict__ src = vv ? sl1 : sl0;
  __half* __restrict__ dst = vv ? Sl1 : Sl0;
  const float* sp = src + ((size_t)(b * 2048 + cg * 32)) * 144;
#pragma unroll
  for (int it = 0; it < 5; ++it) {      // 1152 float4 tasks: 32ch x 36
    int u = t + it * 256;
    if (u < 1152) {
      int c = u / 36;
      int yx = (u - c * 36) * 4;
      float4 v = *reinterpret_cast<const float4*>(sp + (size_t)u * 4);
      smem_h[(yx + 0) * 36 + c] = __float2half(v.x * 10.f);
      smem_h[(yx + 1) * 36 + c] = __float2half(v.y * 10.f);
      smem_h[(yx + 2) * 36 + c] = __float2half(v.z * 10.f);
      smem_h[(yx + 3) * 36 + c] = __float2half(v.w * 10.f);
    }
  }
  __syncthreads();
#pragma unroll
  for (int it = 0; it < 3; ++it) {      // 576 write tasks: 144yx x 4lq
    int u = t + it * 256;
    if (u < 576) {
      int pos = u >> 2, lq = u & 3;
      uint2 a = *reinterpret_cast<const uint2*>(&smem_h[pos * 36 + lq * 8]);
      uint2 b2 = *reinterpret_cast<const uint2*>(&smem_h[pos * 36 + lq * 8 + 4]);
      *reinterpret_cast<uint4*>(dst + ((size_t)(b * 144 + pos)) * 2048 +
                                cg * 32 + lq * 8) = make_uint4(a.x, a.y, b2.x, b2.y);
    }
  }
}

// ===== probs: per-texel softmax from fp16 raw teacher -> Tp fp16 =====
__global__ __launch_bounds__(256) void dino_probs(
    const __half* __restrict__ Tch, __half* __restrict__ Tp,
    const float* __restrict__ cen, const int* __restrict__ ep) {
  __shared__ float rm[4], rs[4];
  int tex = blockIdx.x;                 // [0,3584)
  int t = threadIdx.x;
  int lane = t & 63, w = t >> 6;
  float invtemp = get_invtemp(ep);

  union { uint4 u; __half2 h[4]; } hv;
  hv.u = *reinterpret_cast<const uint4*>(Tch + (size_t)tex * 2048 + t * 8);
  float4 c0 = *reinterpret_cast<const float4*>(cen + t * 8);
  float4 c1 = *reinterpret_cast<const float4*>(cen + t * 8 + 4);
  float lg[8];
  {
    float2 f0 = __half22float2(hv.h[0]), f1 = __half22float2(hv.h[1]);
    float2 f2 = __half22float2(hv.h[2]), f3 = __half22float2(hv.h[3]);
    lg[0] = (f0.x - c0.x) * invtemp; lg[1] = (f0.y - c0.y) * invtemp;
    lg[2] = (f1.x - c0.z) * invtemp; lg[3] = (f1.y - c0.w) * invtemp;
    lg[4] = (f2.x - c1.x) * invtemp; lg[5] = (f2.y - c1.y) * invtemp;
    lg[6] = (f3.x - c1.z) * invtemp; lg[7] = (f3.y - c1.w) * invtemp;
  }
  float m = lg[0];
#pragma unroll
  for (int q = 1; q < 8; ++q) m = fmaxf(m, lg[q]);
#pragma unroll
  for (int off = 32; off; off >>= 1) m = fmaxf(m, __shfl_xor(m, off));
  if (lane == 0) rm[w] = m;
  __syncthreads();
  float M = fmaxf(fmaxf(rm[0], rm[1]), fmaxf(rm[2], rm[3]));

  float e[8];
  float s = 0.f;
#pragma unroll
  for (int q = 0; q < 8; ++q) { e[q] = __expf(lg[q] - M); s += e[q]; }
#pragma unroll
  for (int off = 32; off; off >>= 1) s += __shfl_xor(s, off);
  if (lane == 0) rs[w] = s;
  __syncthreads();
  float invS = 1.f / (rs[0] + rs[1] + rs[2] + rs[3]);

  __half o[8];
#pragma unroll
  for (int q = 0; q < 8; ++q) o[q] = __float2half(e[q] * invS);
  *reinterpret_cast<uint4*>(Tp + (size_t)tex * 2048 + t * 8) =
      *reinterpret_cast<uint4*>(o);
}

// ===== main: 1 wave per position, compact layouts (unchanged, validated) =====
union H8 { uint4 u; __half2 h[4]; };

__global__ __launch_bounds__(256) void dino_main(
    const __half* __restrict__ Tp,
    const __half* __restrict__ S0, const __half* __restrict__ S1,
    const __half* __restrict__ S2, const __half* __restrict__ S3,
    float* __restrict__ losses) {
  int wid = threadIdx.x >> 6, lane = threadIdx.x & 63;
  int pair = blockIdx.x / 1200;
  int slot = blockIdx.x - pair * 1200;
  PairInfo pi = g_pairs[pair];
  int posInPair = slot * 4 + wid;
  if (posInPair >= pi.per * 8) return;

  unsigned up = (unsigned)posInPair;
  int b = (int)__umulhi(up, pi.magicPer);
  b = min(max(b, 0), 7);
  int r = posInPair - b * pi.per;
  r = min(max(r, 0), pi.per - 1);
  int i = (int)__umulhi((unsigned)r, pi.magicW);
  i = min(max(i, 0), pi.gH - 1);
  int j = r - i * pi.gW;
  j = min(max(j, 0), pi.gW - 1);

  // reference swaps gx/gy: image COLUMN from y-linspace (i), ROW from x-linspace (j)
  float tyy = pi.ty1 + (float)i * (pi.ty2 - pi.ty1) / (float)(pi.gH - 1);
  float txx = pi.tx1 + (float)j * (pi.tx2 - pi.tx1) / (float)(pi.gW - 1);
  float tix = fminf(fmaxf((tyy + 1.0f) * 16.0f - 0.5f, 0.0f), 31.0f);
  float tiy = fminf(fmaxf((txx + 1.0f) * 16.0f - 0.5f, 0.0f), 31.0f);
  int tx0 = (int)tix, ty0 = (int)tiy;
  float wxt = tix - (float)tx0, wyt = tiy - (float)ty0;
  int tx1i = min(tx0 + 1, 31), ty1i = min(ty0 + 1, 31);

  int hs = pi.Hs;
  float hh = 0.5f * (float)hs, hm = (float)(hs - 1);
  float syy = pi.sy1 + (float)i * (pi.sy2 - pi.sy1) / (float)(pi.gH - 1);
  float sxx = pi.sx1 + (float)j * (pi.sx2 - pi.sx1) / (float)(pi.gW - 1);
  float six = fminf(fmaxf((syy + 1.0f) * hh - 0.5f, 0.0f), hm);
  float siy = fminf(fmaxf((sxx + 1.0f) * hh - 0.5f, 0.0f), hm);
  int sx0 = (int)six, sy0 = (int)siy;
  float wxs = six - (float)sx0, wys = siy - (float)sy0;
  int sx1i = min(sx0 + 1, hs - 1), sy1i = min(sy0 + 1, hs - 1);

  const __half* __restrict__ S =
      (pi.v == 0) ? S0 : (pi.v == 1) ? S1 : (pi.v == 2) ? S2 : S3;

  int tc0 = min(max(tx0 - pi.tCb, 0), pi.tN - 1);
  int tc1 = min(max(tx1i - pi.tCb, 0), pi.tN - 1);
  int trow = pi.tOfs + (b * 32 + ty0) * pi.tN;
  int trow1 = pi.tOfs + (b * 32 + ty1i) * pi.tN;
  int toff00 = min(trow + tc0, 3583) * 2048;
  int toff01 = min(trow + tc1, 3583) * 2048;
  int toff10 = min(trow1 + tc0, 3583) * 2048;
  int toff11 = min(trow1 + tc1, 3583) * 2048;
  int sc0 = min(max(sx0 - pi.sCb, 0), pi.sN - 1);
  int sc1 = min(max(sx1i - pi.sCb, 0), pi.sN - 1);
  int soff00 = ((b * hs + sy0) * pi.sN + sc0) * 2048;
  int soff01 = ((b * hs + sy0) * pi.sN + sc1) * 2048;
  int soff10 = ((b * hs + sy1i) * pi.sN + sc0) * 2048;
  int soff11 = ((b * hs + sy1i) * pi.sN + sc1) * 2048;

  __half2 wt00 = __float2half2_rn((1.f - wyt) * (1.f - wxt));
  __half2 wt01 = __float2half2_rn((1.f - wyt) * wxt);
  __half2 wt10 = __float2half2_rn(wyt * (1.f - wxt));
  __half2 wt11 = __float2half2_rn(wyt * wxt);
  __half2 ws00 = __float2half2_rn((1.f - wys) * (1.f - wxs));
  __half2 ws01 = __float2half2_rn((1.f - wys) * wxs);
  __half2 ws10 = __float2half2_rn(wys * (1.f - wxs));
  __half2 ws11 = __float2half2_rn(wys * wxs);

  float sum = 0.f, dot = 0.f;
#pragma unroll
  for (int k = 0; k < 4; ++k) {
    int c0 = (k << 9) + (lane << 3);
    H8 t00, t01, t10, t11, a00, a01, a10, a11;
    t00.u = *reinterpret_cast<const uint4*>(Tp + toff00 + c0);
    t01.u = *reinterpret_cast<const uint4*>(Tp + toff01 + c0);
    t10.u = *reinterpret_cast<const uint4*>(Tp + toff10 + c0);
    t11.u = *reinterpret_cast<const uint4*>(Tp + toff11 + c0);
    a00.u = *reinterpret_cast<const uint4*>(S + soff00 + c0);
    a01.u = *reinterpret_cast<const uint4*>(S + soff01 + c0);
    a10.u = *reinterpret_cast<const uint4*>(S + soff10 + c0);
    a11.u = *reinterpret_cast<const uint4*>(S + soff11 + c0);
#pragma unroll
    for (int p = 0; p < 4; ++p) {
      __half2 tc2 = __hmul2(wt00, t00.h[p]);
      tc2 = __hfma2(wt01, t01.h[p], tc2);
      tc2 = __hfma2(wt10, t10.h[p], tc2);
      tc2 = __hfma2(wt11, t11.h[p], tc2);
      __half2 sc2 = __hmul2(ws00, a00.h[p]);
      sc2 = __hfma2(ws01, a01.h[p], sc2);
      sc2 = __hfma2(ws10, a10.h[p], sc2);
      sc2 = __hfma2(ws11, a11.h[p], sc2);
      dot = fdot2f(tc2, sc2, dot);
      float2 scf = __half22float2(sc2);
      sum += __expf(scf.x);
      sum += __expf(scf.y);
    }
  }
#pragma unroll
  for (int off = 32; off; off >>= 1) {
    sum += __shfl_down(sum, off);
    dot += __shfl_down(dot, off);
  }
  if (lane == 0) losses[pi.base + posInPair] = logf(sum) - dot;
}

// ===== final mean =====
__global__ __launch_bounds__(1024) void dino_reduce(const float* __restrict__ losses,
                                                    float* __restrict__ out) {
  __shared__ double sd[1024];
  int t = threadIdx.x;
  double a = 0.0;
  for (int i4 = t; i4 < 6672; i4 += 1024) {
    float4 v = *reinterpret_cast<const float4*>(losses + i4 * 4);
    a += (double)v.x + (double)v.y + (double)v.z + (double)v.w;
  }
  sd[t] = a;
  __syncthreads();
  for (int off = 512; off; off >>= 1) {
    if (t < off) sd[t] += sd[t + off];
    __syncthreads();
  }
  if (t == 0) out[0] = (float)(sd[0] / (double)NPOS);
}

extern "C" void kernel_launch(void* const* d_in, const int* in_sizes, int n_in,
                              void* d_out, int out_size, void* d_ws, size_t ws_size,
                              hipStream_t stream) {
  const float* sg0 = (const float*)d_in[0];
  const float* sg1 = (const float*)d_in[1];
  const float* sl0 = (const float*)d_in[2];
  const float* sl1 = (const float*)d_in[3];
  const float* tg0 = (const float*)d_in[4];
  const float* tg1 = (const float*)d_in[5];
  const float* cen = (const float*)d_in[6];
  const int* epoch = (const int*)d_in[7];
  float* out = (float*)d_out;
  char* w = (char*)d_ws;

  // ws layout (bytes), total 87,293,952 (>=143.9 MB proven available in round 1)
  const size_t OFF_LOSS = 131072;       // 106752 (pad to 262144)
  const size_t OFF_TCH  = 262144;       // 14,680,064 (3584 x 2048 fp16 raw teacher)
  const size_t OFF_TP   = 14942208;     // 14,680,064 (3584 x 2048 fp16 probs)
  const size_t OFF_SG0  = 29622272;     // 25,165,824 (8*32*24*2048 fp16)
  const size_t OFF_SG1  = 54788096;     // 23,068,672 (8*32*22*2048 fp16)
  const size_t OFF_SL0  = 77856768;     // 4,718,592
  const size_t OFF_SL1  = 82575360;     // 4,718,592

  float* losses = (float*)(w + OFF_LOSS);
  __half* Tch = (__half*)(w + OFF_TCH);
  __half* Tp  = (__half*)(w + OFF_TP);
  __half* Sg0 = (__half*)(w + OFF_SG0);
  __half* Sg1 = (__half*)(w + OFF_SG1);
  __half* Sl0 = (__half*)(w + OFF_SL0);
  __half* Sl1 = (__half*)(w + OFF_SL1);

  // phase1 grid: teacher[0,1024) | sg[1024,3072) | sl[3072,4096)
  dino_phase1<<<4096, 256, 0, stream>>>(tg0, tg1, Tch, sg0, sg1, Sg0, Sg1,
                                        sl0, sl1, Sl0, Sl1);
  dino_probs<<<3584, 256, 0, stream>>>(Tch, Tp, cen, epoch);
  dino_main<<<7200, 256, 0, stream>>>(Tp, Sg0, Sg1, Sl0, Sl1, losses);
  dino_reduce<<<1, 1024, 0, stream>>>(losses, out);
}

// Round 12
// 114.221 us; speedup vs baseline: 2.0323x; 1.0684x over previous
//
#include <hip/hip_runtime.h>
#include <hip/hip_fp16.h>

#define NPOS 26688

struct PairInfo {
  int iq, v, Hs, gH, gW, base, per;
  unsigned magicPer, magicW;
  int tOfs, tN, tCb;     // teacher compact: texel offset, #cols, col base
  int sN, sCb;           // student compact: #cols, col base (locals: 12,0)
  float tx1, tx2, ty1, ty2;
  float sx1, sx2, sy1, sy2;
};

// magic = ceil(2^32/d); error-term checked for all used ranges
__constant__ PairInfo g_pairs[6] = {
  {0,1,32,25,24,    0,600, 7158279u,178956971u,    0,2, 7, 22,5, -0.80f,0.70f,-0.500f,-0.475f,  -0.90f,0.60f,-0.60f,0.60f},
  {0,2,12,25,24, 4800,600, 7158279u,178956971u,  512,2,17, 12,0, -0.75f,0.75f, 0.100f, 0.125f,  -0.80f,0.80f,-0.80f,0.80f},
  {0,3,12,22,24, 9600,528, 8134408u,178956971u, 1024,2,12, 12,0, -0.60f,0.90f,-0.200f,-0.178f,  -0.70f,0.90f,-0.90f,0.70f},
  {1,0,32,22,24,13824,528, 8134408u,178956971u, 1536,2,20, 24,7, -0.70f,0.80f, 0.300f, 0.322f,  -0.85f,0.65f,-0.50f,0.90f},
  {1,2,12,24,22,18048,528, 8134408u,195225787u, 2048,3,13, 12,0, -0.90f,0.50f,-0.100f,-0.076f,  -0.60f,0.95f,-0.95f,0.60f},
  {1,3,12,24,23,22272,552, 7780739u,186737709u, 2816,3,18, 12,0, -0.50f,0.95f, 0.200f, 0.224f,  -0.90f,0.90f,-0.40f,0.95f},
};

// compact-teacher write tables; view strictly in [0,2)
__constant__ int g_tentX[2][8] = {
  { 7, 8,12,13,17,18,-100,-100},
  {13,14,15,18,19,20,  20,  21},
};
__constant__ int g_tentO[2][8] = {
  {   0,   0,1024,1024, 512, 512,   0,   0},
  {2048,2048,2048,2816,2816,2816,1536,1536},
};
__constant__ int g_tentN[2][8] = {
  {2,2,2,2,2,2,2,2},
  {3,3,3,3,3,3,2,2},
};
__constant__ int g_tentC[2][8] = {
  {0,1,0,1,0,1,0,0},
  {0,1,2,0,1,2,0,1},
};
// probs-kernel texel decode tables
__constant__ int g_cumTex[6] = {0, 512, 1024, 1536, 2048, 2816};
__constant__ int g_tN[6]    = {2, 2, 2, 2, 3, 3};
__constant__ int g_tCb[6]   = {7, 17, 12, 20, 13, 18};

__device__ inline float get_invtemp(const int* __restrict__ ep) {
  int e = ep[0];
  e = e < 0 ? 0 : (e > 99 ? 99 : e);
  float temp = (e < 30) ? (0.04f + (float)e * (0.03f / 29.0f)) : 0.07f;
  return 1.0f / temp;
}

__device__ inline float sel4(const float4& v, int q) {
  return q == 0 ? v.x : q == 1 ? v.y : q == 2 ? v.z : v.w;
}

typedef _Float16 hv2 __attribute__((ext_vector_type(2)));
__device__ inline float fdot2f(__half2 a, __half2 b, float c) {
#if defined(__has_builtin)
#if __has_builtin(__builtin_amdgcn_fdot2)
  return __builtin_amdgcn_fdot2(*reinterpret_cast<hv2*>(&a),
                                *reinterpret_cast<hv2*>(&b), c, false);
#else
  float2 af = __half22float2(a), bf = __half22float2(b);
  return fmaf(af.x, bf.x, fmaf(af.y, bf.y, c));
#endif
#else
  float2 af = __half22float2(a), bf = __half22float2(b);
  return fmaf(af.x, bf.x, fmaf(af.y, bf.y, c));
#endif
}

// =========== phase1: stats(4096) | t12(2048) | t32(13312) — fused ===========
__global__ __launch_bounds__(256) void dino_phase1(
    const float* __restrict__ tg0, const float* __restrict__ tg1,
    const float* __restrict__ cen, const int* __restrict__ ep,
    float* __restrict__ part_m, float* __restrict__ part_s,
    __half* __restrict__ Tc,
    const float* __restrict__ sl0, const float* __restrict__ sl1,
    __half* __restrict__ Sl0, __half* __restrict__ Sl1,
    const float* __restrict__ sg0, const float* __restrict__ sg1,
    __half* __restrict__ Sg0, __half* __restrict__ Sg1) {
  __shared__ float smem[2960];          // 11840 B, aliased per branch
  int bid = blockIdx.x;
  int t = threadIdx.x;

  if (bid < 4096) {
    // ---------- teacher stats + compact dLogit write ----------
    // 4096 = view(2)*b(8)*y(32)*chunk(8)
    int chunk = bid & 7;
    int y = (bid >> 3) & 31;
    int b = (bid >> 8) & 7;
    int view = bid >> 11;               // in [0,2)
    const float* __restrict__ src = view ? tg1 : tg0;
    float invtemp = get_invtemp(ep);

    float* cenl = smem;                 // 256
    float* pm   = smem + 256;           // 32*33 = 1056
    float* ps   = smem + 1312;          // 1056
    float* pm2  = smem + 2368;          // 8*33 = 264
    float* ps2  = smem + 2632;          // 264
    float* cm   = smem + 2896;          // 32

    cenl[t] = cen[chunk * 256 + t];
    __syncthreads();

    int xg = t & 7, sub = t >> 3;       // x = xg*4..xg*4+3, sub in [0,32)
    const float* sp = src + (((size_t)(b * 2048 + chunk * 256 + sub)) * 32 + y) * 32 + xg * 4;
    float4 lg[8];
#pragma unroll
    for (int k = 0; k < 8; ++k) {
      float4 v = *reinterpret_cast<const float4*>(sp + (size_t)k * 32768);
      float cv = cenl[k * 32 + sub];
      lg[k].x = (v.x - cv) * invtemp;
      lg[k].y = (v.y - cv) * invtemp;
      lg[k].z = (v.z - cv) * invtemp;
      lg[k].w = (v.w - cv) * invtemp;
    }
    float4 mx = lg[0];
#pragma unroll
    for (int k = 1; k < 8; ++k) {
      mx.x = fmaxf(mx.x, lg[k].x); mx.y = fmaxf(mx.y, lg[k].y);
      mx.z = fmaxf(mx.z, lg[k].z); mx.w = fmaxf(mx.w, lg[k].w);
    }
    float4 s = make_float4(0.f, 0.f, 0.f, 0.f);
#pragma unroll
    for (int k = 0; k < 8; ++k) {
      s.x += __expf(lg[k].x - mx.x); s.y += __expf(lg[k].y - mx.y);
      s.z += __expf(lg[k].z - mx.z); s.w += __expf(lg[k].w - mx.w);
    }
    pm[sub * 33 + xg * 4 + 0] = mx.x; ps[sub * 33 + xg * 4 + 0] = s.x;
    pm[sub * 33 + xg * 4 + 1] = mx.y; ps[sub * 33 + xg * 4 + 1] = s.y;
    pm[sub * 33 + xg * 4 + 2] = mx.z; ps[sub * 33 + xg * 4 + 2] = s.z;
    pm[sub * 33 + xg * 4 + 3] = mx.w; ps[sub * 33 + xg * 4 + 3] = s.w;
    __syncthreads();
    // tree merge level 1: 8 groups x 4 subs, all 256 threads
    {
      int x = t & 31, g = t >> 5;
      float m0 = pm[(g * 4 + 0) * 33 + x], m1 = pm[(g * 4 + 1) * 33 + x];
      float m2 = pm[(g * 4 + 2) * 33 + x], m3 = pm[(g * 4 + 3) * 33 + x];
      float M = fmaxf(fmaxf(m0, m1), fmaxf(m2, m3));
      float S = ps[(g * 4 + 0) * 33 + x] * __expf(m0 - M)
              + ps[(g * 4 + 1) * 33 + x] * __expf(m1 - M)
              + ps[(g * 4 + 2) * 33 + x] * __expf(m2 - M)
              + ps[(g * 4 + 3) * 33 + x] * __expf(m3 - M);
      pm2[g * 33 + x] = M; ps2[g * 33 + x] = S;
    }
    __syncthreads();
    if (t < 32) {
      float M = pm2[t];
#pragma unroll
      for (int g = 1; g < 8; ++g) M = fmaxf(M, pm2[g * 33 + t]);
      float S = 0.f;
#pragma unroll
      for (int g = 0; g < 8; ++g) S += ps2[g * 33 + t] * __expf(pm2[g * 33 + t] - M);
      part_m[bid * 32 + t] = M;
      part_s[bid * 32 + t] = S;
      cm[t] = M;                        // chunk max for dLogit write
    }
    __syncthreads();
    // compact teacher dLogits (fp16): only the 14 sampled column-slices
    int nent = view ? 8 : 6;
#pragma unroll
    for (int e = 0; e < 8; ++e) {
      if (e < nent) {
        int ex = g_tentX[view][e];
        if ((ex >> 2) == xg) {
          int q = ex & 3;
          float cmx = cm[ex & 31];
          int tex = g_tentO[view][e] + (b * 32 + y) * g_tentN[view][e] + g_tentC[view][e];
          tex = min(max(tex, 0), 3583);
          size_t base = (size_t)tex * 2048 + chunk * 256 + sub;
#pragma unroll
          for (int k = 0; k < 8; ++k)
            Tc[base + k * 32] = __float2half(sel4(lg[k], q) - cmx);
        }
      }
    }
    return;
  }

  if (bid < 6144) {
    // ---------- student 12x12 transpose, 16 ch/block: 2048 = v(2)*b(8)*ct(128) ----------
    float* tile = smem;                 // 16*145 = 2320
    int lb = bid - 4096;
    int ct = lb & 127;
    int g = lb >> 7;
    int b = g & 7;
    int vv = g >> 3;
    const float* __restrict__ src = vv ? sl1 : sl0;
    __half* __restrict__ dst = vv ? Sl1 : Sl0;
    const float* sp = src + ((size_t)(b * 2048 + ct * 16)) * 144;
#pragma unroll
    for (int k = 0; k < 9; ++k) {       // 2304 contiguous floats in
      int idx = t + 256 * k;
      int c = idx / 144;
      int yx = idx - c * 144;
      tile[c * 145 + yx] = sp[idx] * 10.f;
    }
    __syncthreads();
    __half* dp = dst + ((size_t)(b * 144)) * 2048 + ct * 16;
#pragma unroll
    for (int k = 0; k < 2; ++k) {       // 288 float4 chunks out
      int u = t + 256 * k;
      if (u < 288) {
        int yx = u >> 1, q8 = (u & 1) * 8;
        __half hv[8];
#pragma unroll
        for (int j = 0; j < 8; ++j) hv[j] = __float2half(tile[(q8 + j) * 145 + yx]);
        *reinterpret_cast<float4*>(dp + (size_t)yx * 2048 + q8) =
            *reinterpret_cast<float4*>(hv);
      }
    }
    return;
  }

  // ---------- student-global windowed transpose: 13312 = which(2)*b(8)*y(26)*ct(32) ----------
  float* tile = smem;                   // 64*33 = 2112
  int lb = bid - 6144;
  int ct = lb & 31;
  int t2 = lb >> 5;                     // [0,416)
  int yi = t2 % 26;
  int g = t2 / 26;                      // [0,16)
  int y = yi + 1;                       // rows 1..26 only (sampled window)
  int b = g & 7;
  int which = g >> 3;
  const float* __restrict__ src = which ? sg1 : sg0;
  __half* __restrict__ dst = which ? Sg1 : Sg0;
  int cb = which ? 5 : 7;
  int n = which ? 22 : 24;

  int xg = t & 7, ch = t >> 3;
  const float* sp = src + (((size_t)(b * 2048 + ct * 64 + ch)) * 32 + y) * 32 + xg * 4;
  float4 v0 = *reinterpret_cast<const float4*>(sp);
  float4 v1 = *reinterpret_cast<const float4*>(sp + 32768);
  tile[ch * 33 + xg * 4 + 0] = v0.x * 10.f;
  tile[ch * 33 + xg * 4 + 1] = v0.y * 10.f;
  tile[ch * 33 + xg * 4 + 2] = v0.z * 10.f;
  tile[ch * 33 + xg * 4 + 3] = v0.w * 10.f;
  tile[(ch + 32) * 33 + xg * 4 + 0] = v1.x * 10.f;
  tile[(ch + 32) * 33 + xg * 4 + 1] = v1.y * 10.f;
  tile[(ch + 32) * 33 + xg * 4 + 2] = v1.z * 10.f;
  tile[(ch + 32) * 33 + xg * 4 + 3] = v1.w * 10.f;
  __syncthreads();
  int xx = t >> 3, ccq = (t & 7) * 8;
  if (xx >= cb && xx < cb + n) {
    __half hv[8];
#pragma unroll
    for (int j = 0; j < 8; ++j) hv[j] = __float2half(tile[(ccq + j) * 33 + xx]);
    __half* dp = dst + ((size_t)((b * 32 + y) * n + (xx - cb))) * 2048 + ct * 64 + ccq;
    *reinterpret_cast<float4*>(dp) = *reinterpret_cast<float4*>(hv);
  }
}

// =========== probs: Tc dlogits -> Tp probs, self-merging partials ===========
union H8 { uint4 u; __half2 h[4]; };

__global__ __launch_bounds__(256) void dino_probs(
    const __half* __restrict__ Tc, __half* __restrict__ Tp,
    const float* __restrict__ part_m, const float* __restrict__ part_s) {
  __shared__ float pm8[8], ps8[8];
  int bid = blockIdx.x;                 // 3584 texels
  int t = threadIdx.x;
  int p = 0;
#pragma unroll
  for (int q = 1; q < 6; ++q) p += (bid >= g_cumTex[q]) ? 1 : 0;
  int r = bid - g_cumTex[p];
  int n = g_tN[p];
  int by = (n == 2) ? (r >> 1) : (r / 3);
  by = min(max(by, 0), 255);
  int ci = min(max(r - by * n, 0), n - 1);
  int x = g_tCb[p] + ci;                // <= 21 < 32
  int view = (p >= 3) ? 1 : 0;
  int b = by >> 5, y = by & 31;
  int texRow = ((view * 8 + b) * 32 + y);        // < 512
  if (t < 8) {
    pm8[t] = part_m[(texRow * 8 + t) * 32 + x];
    ps8[t] = part_s[(texRow * 8 + t) * 32 + x];
  }
  __syncthreads();
  float M = pm8[0];
#pragma unroll
  for (int c = 1; c < 8; ++c) M = fmaxf(M, pm8[c]);
  float S = 0.f;
#pragma unroll
  for (int c = 0; c < 8; ++c) S += ps8[c] * __expf(pm8[c] - M);
  float invS = 1.f / S;
  float off = pm8[t >> 5] - M;

  int tex = min(g_cumTex[p] + by * n + ci, 3583);
  size_t base = (size_t)tex * 2048 + t * 8;
  H8 hh;
  hh.u = *reinterpret_cast<const uint4*>(Tc + base);
#pragma unroll
  for (int pc = 0; pc < 4; ++pc) {
    float2 f = __half22float2(hh.h[pc]);
    f.x = __expf(f.x + off) * invS;
    f.y = __expf(f.y + off) * invS;
    hh.h[pc] = __floats2half2_rn(f.x, f.y);
  }
  *reinterpret_cast<uint4*>(Tp + base) = hh.u;
}

// =========== main: 1 wave per position, compact layouts ===========
__global__ __launch_bounds__(256) void dino_main(
    const __half* __restrict__ Tp,
    const __half* __restrict__ S0, const __half* __restrict__ S1,
    const __half* __restrict__ S2, const __half* __restrict__ S3,
    float* __restrict__ losses) {
  int wid = threadIdx.x >> 6, lane = threadIdx.x & 63;
  int pair = blockIdx.x / 1200;
  int slot = blockIdx.x - pair * 1200;
  PairInfo pi = g_pairs[pair];
  int posInPair = slot * 4 + wid;
  if (posInPair >= pi.per * 8) return;

  unsigned up = (unsigned)posInPair;
  int b = (int)__umulhi(up, pi.magicPer);
  b = min(max(b, 0), 7);
  int r = posInPair - b * pi.per;
  r = min(max(r, 0), pi.per - 1);
  int i = (int)__umulhi((unsigned)r, pi.magicW);
  i = min(max(i, 0), pi.gH - 1);
  int j = r - i * pi.gW;
  j = min(max(j, 0), pi.gW - 1);

  // reference swaps gx/gy: image COLUMN from y-linspace (i), ROW from x-linspace (j)
  float tyy = pi.ty1 + (float)i * (pi.ty2 - pi.ty1) / (float)(pi.gH - 1);
  float txx = pi.tx1 + (float)j * (pi.tx2 - pi.tx1) / (float)(pi.gW - 1);
  float tix = fminf(fmaxf((tyy + 1.0f) * 16.0f - 0.5f, 0.0f), 31.0f);
  float tiy = fminf(fmaxf((txx + 1.0f) * 16.0f - 0.5f, 0.0f), 31.0f);
  int tx0 = (int)tix, ty0 = (int)tiy;
  float wxt = tix - (float)tx0, wyt = tiy - (float)ty0;
  int tx1i = min(tx0 + 1, 31), ty1i = min(ty0 + 1, 31);

  int hs = pi.Hs;
  float hh = 0.5f * (float)hs, hm = (float)(hs - 1);
  float syy = pi.sy1 + (float)i * (pi.sy2 - pi.sy1) / (float)(pi.gH - 1);
  float sxx = pi.sx1 + (float)j * (pi.sx2 - pi.sx1) / (float)(pi.gW - 1);
  float six = fminf(fmaxf((syy + 1.0f) * hh - 0.5f, 0.0f), hm);
  float siy = fminf(fmaxf((sxx + 1.0f) * hh - 0.5f, 0.0f), hm);
  int sx0 = (int)six, sy0 = (int)siy;
  float wxs = six - (float)sx0, wys = siy - (float)sy0;
  int sx1i = min(sx0 + 1, hs - 1), sy1i = min(sy0 + 1, hs - 1);

  const __half* __restrict__ S =
      (pi.v == 0) ? S0 : (pi.v == 1) ? S1 : (pi.v == 2) ? S2 : S3;

  int tc0 = min(max(tx0 - pi.tCb, 0), pi.tN - 1);
  int tc1 = min(max(tx1i - pi.tCb, 0), pi.tN - 1);
  int trow = pi.tOfs + (b * 32 + ty0) * pi.tN;
  int trow1 = pi.tOfs + (b * 32 + ty1i) * pi.tN;
  int toff00 = min(trow + tc0, 3583) * 2048;
  int toff01 = min(trow + tc1, 3583) * 2048;
  int toff10 = min(trow1 + tc0, 3583) * 2048;
  int toff11 = min(trow1 + tc1, 3583) * 2048;
  int sc0 = min(max(sx0 - pi.sCb, 0), pi.sN - 1);
  int sc1 = min(max(sx1i - pi.sCb, 0), pi.sN - 1);
  int soff00 = ((b * hs + sy0) * pi.sN + sc0) * 2048;
  int soff01 = ((b * hs + sy0) * pi.sN + sc1) * 2048;
  int soff10 = ((b * hs + sy1i) * pi.sN + sc0) * 2048;
  int soff11 = ((b * hs + sy1i) * pi.sN + sc1) * 2048;

  __half2 wt00 = __float2half2_rn((1.f - wyt) * (1.f - wxt));
  __half2 wt01 = __float2half2_rn((1.f - wyt) * wxt);
  __half2 wt10 = __float2half2_rn(wyt * (1.f - wxt));
  __half2 wt11 = __float2half2_rn(wyt * wxt);
  __half2 ws00 = __float2half2_rn((1.f - wys) * (1.f - wxs));
  __half2 ws01 = __float2half2_rn((1.f - wys) * wxs);
  __half2 ws10 = __float2half2_rn(wys * (1.f - wxs));
  __half2 ws11 = __float2half2_rn(wys * wxs);

  float sum = 0.f, dot = 0.f;
#pragma unroll
  for (int k = 0; k < 4; ++k) {
    int c0 = (k << 9) + (lane << 3);
    H8 t00, t01, t10, t11, a00, a01, a10, a11;
    t00.u = *reinterpret_cast<const uint4*>(Tp + toff00 + c0);
    t01.u = *reinterpret_cast<const uint4*>(Tp + toff01 + c0);
    t10.u = *reinterpret_cast<const uint4*>(Tp + toff10 + c0);
    t11.u = *reinterpret_cast<const uint4*>(Tp + toff11 + c0);
    a00.u = *reinterpret_cast<const uint4*>(S + soff00 + c0);
    a01.u = *reinterpret_cast<const uint4*>(S + soff01 + c0);
    a10.u = *reinterpret_cast<const uint4*>(S + soff10 + c0);
    a11.u = *reinterpret_cast<const uint4*>(S + soff11 + c0);
#pragma unroll
    for (int p = 0; p < 4; ++p) {
      __half2 tc2 = __hmul2(wt00, t00.h[p]);
      tc2 = __hfma2(wt01, t01.h[p], tc2);
      tc2 = __hfma2(wt10, t10.h[p], tc2);
      tc2 = __hfma2(wt11, t11.h[p], tc2);
      __half2 sc2 = __hmul2(ws00, a00.h[p]);
      sc2 = __hfma2(ws01, a01.h[p], sc2);
      sc2 = __hfma2(ws10, a10.h[p], sc2);
      sc2 = __hfma2(ws11, a11.h[p], sc2);
      dot = fdot2f(tc2, sc2, dot);
      float2 scf = __half22float2(sc2);
      sum += __expf(scf.x);
      sum += __expf(scf.y);
    }
  }
#pragma unroll
  for (int off = 32; off; off >>= 1) {
    sum += __shfl_down(sum, off);
    dot += __shfl_down(dot, off);
  }
  if (lane == 0) losses[pi.base + posInPair] = logf(sum) - dot;
}

// =========== final mean ===========
__global__ __launch_bounds__(1024) void dino_reduce(const float* __restrict__ losses,
                                                    float* __restrict__ out) {
  __shared__ double sd[1024];
  int t = threadIdx.x;
  double a = 0.0;
  for (int i4 = t; i4 < 6672; i4 += 1024) {
    float4 v = *reinterpret_cast<const float4*>(losses + i4 * 4);
    a += (double)v.x + (double)v.y + (double)v.z + (double)v.w;
  }
  sd[t] = a;
  __syncthreads();
  for (int off = 512; off; off >>= 1) {
    if (t < off) sd[t] += sd[t + off];
    __syncthreads();
  }
  if (t == 0) out[0] = (float)(sd[0] / (double)NPOS);
}

extern "C" void kernel_launch(void* const* d_in, const int* in_sizes, int n_in,
                              void* d_out, int out_size, void* d_ws, size_t ws_size,
                              hipStream_t stream) {
  const float* sg0 = (const float*)d_in[0];
  const float* sg1 = (const float*)d_in[1];
  const float* sl0 = (const float*)d_in[2];
  const float* sl1 = (const float*)d_in[3];
  const float* tg0 = (const float*)d_in[4];
  const float* tg1 = (const float*)d_in[5];
  const float* cen = (const float*)d_in[6];
  const int* epoch = (const int*)d_in[7];
  float* out = (float*)d_out;
  char* w = (char*)d_ws;

  // ws layout (bytes), total ~89.4 MB (>=143.9 MB proven available in round 1)
  const size_t OFF_LOSS= 131072;       // 106752 (pad to 262144)
  const size_t OFF_PM  = 262144;       // 512 KB used (4096 rows x 32 f32)
  const size_t OFF_PS  = 1310720;      // 512 KB used
  const size_t OFF_TC  = 2359296;      // 14,680,064 (3584 x 2048 fp16 dlogits)
  const size_t OFF_TP  = 17039360;     // 14,680,064 (3584 x 2048 fp16 probs)
  const size_t OFF_SG0 = 31719424;     // 25,165,824 (8*32*24*2048 fp16)
  const size_t OFF_SG1 = 56885248;     // 23,068,672 (8*32*22*2048 fp16)
  const size_t OFF_SL0 = 79953920;     // 4,718,592
  const size_t OFF_SL1 = 84672512;     // 4,718,592

  float* losses = (float*)(w + OFF_LOSS);
  float* part_m = (float*)(w + OFF_PM);
  float* part_s = (float*)(w + OFF_PS);
  __half* Tc  = (__half*)(w + OFF_TC);
  __half* Tp  = (__half*)(w + OFF_TP);
  __half* Sg0 = (__half*)(w + OFF_SG0);
  __half* Sg1 = (__half*)(w + OFF_SG1);
  __half* Sl0 = (__half*)(w + OFF_SL0);
  __half* Sl1 = (__half*)(w + OFF_SL1);

  // phase1 grid: stats[0,4096) | t12[4096,6144) | t32[6144,19456)
  dino_phase1<<<19456, 256, 0, stream>>>(tg0, tg1, cen, epoch, part_m, part_s, Tc,
                                         sl0, sl1, Sl0, Sl1, sg0, sg1, Sg0, Sg1);
  dino_probs<<<3584, 256, 0, stream>>>(Tc, Tp, part_m, part_s);
  dino_main<<<7200, 256, 0, stream>>>(Tp, Sg0, Sg1, Sl0, Sl1, losses);
  dino_reduce<<<1, 1024, 0, stream>>>(losses, out);
}